// Round 1
// baseline (243.261 us; speedup 1.0000x reference)
//
#include <hip/hip_runtime.h>
#include <hip/hip_bf16.h>

// Attention head: B=32, S=1024 (=32x32), C=D=512, fp32 in/out.
// Decomposition (all raw-reshape friendly, per-batch X is contiguous [1024,512]):
//   1. convert: x -> bf16, Wq*scale/Wk/Wv -> bf16
//   2. gemm_bt<BF16>:  Q = X Wq^T (scaled), K = X Wk^T        (z=2 launches in one)
//   3. gemm_bt<BF16_T>: V^T stored as [b][d][s]               (B^T layout for PV)
//   4. gemm_bt<BF16>:  S = Q K^T per batch  -> bf16 logits
//   5. softmax_rows:   P = softmax(S) in place
//   6. gemm_bt<F32>:   out = P V  (B operand = V^T, K-contiguous both sides)
// GEMM core: m97-style 128x128 tile, BK=64, 4 waves, global_load_lds width 16
// with pre-swizzled global source + XOR-swizzled ds_read_b128 (T2).

typedef __attribute__((ext_vector_type(8))) short short8;
typedef __attribute__((ext_vector_type(4))) float f32x4;

#define GLD16(g, l)                                                         \
  __builtin_amdgcn_global_load_lds(                                         \
      (const __attribute__((address_space(1))) void*)(g),                   \
      (__attribute__((address_space(3))) void*)(l), 16, 0, 0)

__device__ __forceinline__ unsigned short f2bf(float f) {
  unsigned int u = __float_as_uint(f);
  u += 0x7fffu + ((u >> 16) & 1u);   // round-to-nearest-even
  return (unsigned short)(u >> 16);
}

enum { ST_BF16 = 0, ST_BF16_T = 1, ST_F32 = 2 };

// C = A * B^T with A [M x K] row-major (lda), B [N x K] row-major (ldb).
// Grid: x = M/128 tiles, y = N/128 tiles, z = batch (strides in elements).
template <int STORE>
__global__ __launch_bounds__(256) void gemm_bt(
    const unsigned short* __restrict__ A, const unsigned short* __restrict__ B,
    void* __restrict__ Cout, int K, int lda, int ldb, int ldc, long aStride,
    long bStride, long cStride) {
  __shared__ unsigned short As[128 * 64];
  __shared__ unsigned short Bs[128 * 64];

  const int tid = threadIdx.x;
  const int lane = tid & 63;
  const int wm = tid >> 7;        // wave row (0..1)
  const int wn = (tid >> 6) & 1;  // wave col (0..1)

  const unsigned short* Ag =
      A + (long)blockIdx.z * aStride + (long)(blockIdx.x * 128) * lda;
  const unsigned short* Bg =
      B + (long)blockIdx.z * bStride + (long)(blockIdx.y * 128) * ldb;

  f32x4 acc[4][4];
#pragma unroll
  for (int i = 0; i < 4; ++i)
#pragma unroll
    for (int j = 0; j < 4; ++j) acc[i][j] = (f32x4)(0.0f);

  for (int k0 = 0; k0 < K; k0 += 64) {
    // Stage 128x64 bf16 tiles of A and B. Linear LDS dest (wave-uniform base +
    // lane*16), source column-chunk XOR-pre-swizzled so that LDS holds the
    // st-swizzled layout: byte(row,col) = row*128 + (col*2 ^ ((row&7)<<4)).
#pragma unroll
    for (int it = 0; it < 4; ++it) {
      int c = it * 256 + tid;          // 16B chunk index, 1024 per tile
      int row = c >> 3;                // 0..127
      int chk = (c & 7) ^ (row & 7);   // swizzled source chunk
      GLD16(Ag + (long)row * lda + k0 + chk * 8, (char*)As + c * 16);
      GLD16(Bg + (long)row * ldb + k0 + chk * 8, (char*)Bs + c * 16);
    }
    __syncthreads();

#pragma unroll
    for (int kk = 0; kk < 2; ++kk) {
      short8 af[4], bfr[4];
#pragma unroll
      for (int mi = 0; mi < 4; ++mi) {
        int row = wm * 64 + mi * 16 + (lane & 15);
        int colb = (((lane >> 4) * 16) + kk * 64) ^ ((row & 7) << 4);
        af[mi] = *(const short8*)((const char*)As + row * 128 + colb);
      }
#pragma unroll
      for (int ni = 0; ni < 4; ++ni) {
        int row = wn * 64 + ni * 16 + (lane & 15);
        int colb = (((lane >> 4) * 16) + kk * 64) ^ ((row & 7) << 4);
        bfr[ni] = *(const short8*)((const char*)Bs + row * 128 + colb);
      }
#pragma unroll
      for (int mi = 0; mi < 4; ++mi)
#pragma unroll
        for (int ni = 0; ni < 4; ++ni)
          acc[mi][ni] = __builtin_amdgcn_mfma_f32_16x16x32_bf16(
              af[mi], bfr[ni], acc[mi][ni], 0, 0, 0);
    }
    __syncthreads();
  }

  // Epilogue. C/D frag layout (m89-verified): col = lane&15, row = (lane>>4)*4+r
  const int rbase = blockIdx.x * 128 + wm * 64;
  const int cbase = blockIdx.y * 128 + wn * 64;
  const int rl = (lane >> 4) * 4;
  const int cl = lane & 15;

  if (STORE == ST_F32) {
    float* C = (float*)Cout + (long)blockIdx.z * cStride;
#pragma unroll
    for (int mi = 0; mi < 4; ++mi)
#pragma unroll
      for (int ni = 0; ni < 4; ++ni)
#pragma unroll
        for (int r = 0; r < 4; ++r) {
          int row = rbase + mi * 16 + rl + r;
          int col = cbase + ni * 16 + cl;
          C[(long)row * ldc + col] = acc[mi][ni][r];
        }
  } else if (STORE == ST_BF16) {
    unsigned short* C = (unsigned short*)Cout + (long)blockIdx.z * cStride;
#pragma unroll
    for (int mi = 0; mi < 4; ++mi)
#pragma unroll
      for (int ni = 0; ni < 4; ++ni)
#pragma unroll
        for (int r = 0; r < 4; ++r) {
          int row = rbase + mi * 16 + rl + r;
          int col = cbase + ni * 16 + cl;
          C[(long)row * ldc + col] = f2bf(acc[mi][ni][r]);
        }
  } else {  // ST_BF16_T: rows are (b*1024+s), store at [b][col][s]
    unsigned short* C = (unsigned short*)Cout;
#pragma unroll
    for (int mi = 0; mi < 4; ++mi)
#pragma unroll
      for (int ni = 0; ni < 4; ++ni)
#pragma unroll
        for (int r = 0; r < 4; ++r) {
          int row = rbase + mi * 16 + rl + r;
          int col = cbase + ni * 16 + cl;
          C[(long)(row >> 10) * cStride + (long)col * 1024 + (row & 1023)] =
              f2bf(acc[mi][ni][r]);
        }
  }
}

// In-place row softmax over 32768 rows of 1024 bf16. One wave per row.
__global__ __launch_bounds__(256) void softmax_rows(
    unsigned short* __restrict__ S) {
  const long row = (long)blockIdx.x * 4 + (threadIdx.x >> 6);
  const int lane = threadIdx.x & 63;
  unsigned short* p = S + row * 1024 + lane * 16;
  uint4 u0 = *(const uint4*)p;
  uint4 u1 = *(const uint4*)(p + 8);
  unsigned int us[8] = {u0.x, u0.y, u0.z, u0.w, u1.x, u1.y, u1.z, u1.w};
  float v[16];
#pragma unroll
  for (int j = 0; j < 8; ++j) {
    v[2 * j] = __uint_as_float(us[j] << 16);
    v[2 * j + 1] = __uint_as_float(us[j] & 0xffff0000u);
  }
  float m = v[0];
#pragma unroll
  for (int i = 1; i < 16; ++i) m = fmaxf(m, v[i]);
#pragma unroll
  for (int off = 32; off >= 1; off >>= 1) m = fmaxf(m, __shfl_xor(m, off, 64));
  float s = 0.0f;
#pragma unroll
  for (int i = 0; i < 16; ++i) {
    v[i] = __expf(v[i] - m);
    s += v[i];
  }
#pragma unroll
  for (int off = 32; off >= 1; off >>= 1) s += __shfl_xor(s, off, 64);
  const float inv = 1.0f / s;
#pragma unroll
  for (int j = 0; j < 8; ++j) {
    unsigned int lo = f2bf(v[2 * j] * inv);
    unsigned int hi = f2bf(v[2 * j + 1] * inv);
    us[j] = lo | (hi << 16);
  }
  uint4 o0 = {us[0], us[1], us[2], us[3]};
  uint4 o1 = {us[4], us[5], us[6], us[7]};
  *(uint4*)p = o0;
  *(uint4*)(p + 8) = o1;
}

// Convert x (16.78M f32) and the three 512x512 weights to bf16 (Wq pre-scaled
// by 1/sqrt(512)). One float4 per thread, exact grid.
__global__ __launch_bounds__(256) void convert_in(
    const float* __restrict__ x, const float* __restrict__ wq,
    const float* __restrict__ wk, const float* __restrict__ wv,
    unsigned short* __restrict__ xb, unsigned short* __restrict__ wb) {
  const long i = (long)blockIdx.x * 256 + threadIdx.x;
  const long NX4 = 16777216 / 4;
  const float* src;
  unsigned short* dst;
  long off;
  float sc = 1.0f;
  if (i < NX4) {
    src = x;
    dst = xb;
    off = i;
  } else {
    long r = i - NX4;
    int w = (int)(r >> 16);  // 65536 float4 groups per weight
    off = r & 65535;
    src = (w == 0) ? wq : (w == 1) ? wk : wv;
    dst = wb + (long)w * 262144;
    if (w == 0) sc = 0.044194173824159216f;  // 1/sqrt(512)
  }
  float4 f = ((const float4*)src)[off];
  ushort4 o;
  o.x = f2bf(f.x * sc);
  o.y = f2bf(f.y * sc);
  o.z = f2bf(f.z * sc);
  o.w = f2bf(f.w * sc);
  ((ushort4*)dst)[off] = o;
}

extern "C" void kernel_launch(void* const* d_in, const int* in_sizes, int n_in,
                              void* d_out, int out_size, void* d_ws,
                              size_t ws_size, hipStream_t stream) {
  const float* x = (const float*)d_in[0];
  const float* wq = (const float*)d_in[1];
  const float* wk = (const float*)d_in[2];
  const float* wv = (const float*)d_in[3];
  float* out = (float*)d_out;

  // Workspace layout (elements of bf16/ushort):
  unsigned short* xb = (unsigned short*)d_ws;   // 16777216
  unsigned short* wb = xb + 16777216;           // 3*262144 (wq*scale|wk|wv)
  unsigned short* qb = wb + 786432;             // 16777216 (Q, scaled)
  unsigned short* kb = qb + 16777216;           // 16777216 (K)  [contiguous after Q]
  unsigned short* vtb = kb + 16777216;          // 16777216 (V^T per batch [d][s])
  unsigned short* sb = vtb + 16777216;          // 33554432 (S -> P in place)
  // total = 194 MiB of d_ws

  // 1. convert inputs to bf16
  convert_in<<<17152, 256, 0, stream>>>(x, wq, wk, wv, xb, wb);

  // 2. Q,K = X * {Wq_s, Wk}^T : M=32768, N=512, K=512; z picks matrix
  {
    dim3 g(256, 4, 2);
    gemm_bt<ST_BF16><<<g, 256, 0, stream>>>(xb, wb, qb, 512, 512, 512, 512, 0L,
                                            262144L, 16777216L);
  }
  // 3. V^T = (X * Wv^T)^T stored [b][d][s]
  {
    dim3 g(256, 4, 1);
    gemm_bt<ST_BF16_T><<<g, 256, 0, stream>>>(xb, wb + 524288, vtb, 512, 512,
                                              512, 512, 0L, 0L, 524288L);
  }
  // 4. S = Q K^T per batch: M=N=1024, K=512 (scale folded into Wq)
  {
    dim3 g(8, 8, 32);
    gemm_bt<ST_BF16><<<g, 256, 0, stream>>>(qb, kb, sb, 512, 512, 512, 1024,
                                            524288L, 524288L, 1048576L);
  }
  // 5. softmax rows in place (32768 rows x 1024)
  softmax_rows<<<8192, 256, 0, stream>>>(sb);

  // 6. out = P V : A=P [1024x1024], B=V^T [512x1024], K=1024, f32 store
  {
    dim3 g(8, 4, 32);
    gemm_bt<ST_F32><<<g, 256, 0, stream>>>(sb, vtb, out, 1024, 1024, 1024, 512,
                                           1048576L, 524288L, 524288L);
  }
}

// Round 2
// 228.157 us; speedup vs baseline: 1.0662x; 1.0662x over previous
//
#include <hip/hip_runtime.h>
#include <hip/hip_bf16.h>

// B=32, S=1024, C=D=512 attention, fp32 in/out.
//   1. convert: x -> bf16; [Wq*scale | Wk | Wv] -> bf16 (contiguous 1536x512)
//   2. gemm8p<QKV>:  [Q|K|V] = X W'^T, one GEMM M=32768 N=1536 K=512;
//      epilogue routes Q->qb, K->kb, V->vtb ([b][d][s] transposed)
//   3. gemm8p<BF16>: S = Q K^T per batch (scale folded into Wq)
//   4. softmax_rows: P = softmax(S) in place
//   5. gemm8p<F32>:  out = P V   (B operand = V^T, K-contiguous both sides)
//
// gemm8p: 256x256 tile, BK=64, 8 waves (2M x 4N interleaved), 128 KiB LDS
// double-buffer, 4 quadrant-phases per K-tile with counted s_waitcnt vmcnt(4)
// (never 0 in the loop), raw s_barrier, setprio(1) around MFMA clusters,
// XOR-swizzled LDS (pre-swizzled global source, linear global_load_lds dest).

typedef __attribute__((ext_vector_type(8))) short short8;
typedef __attribute__((ext_vector_type(4))) float f32x4;

#define GLD16(g, l)                                                         \
  __builtin_amdgcn_global_load_lds(                                         \
      (const __attribute__((address_space(1))) void*)(g),                   \
      (__attribute__((address_space(3))) void*)(l), 16, 0, 0)

__device__ __forceinline__ unsigned short f2bf(float f) {
  unsigned int u = __float_as_uint(f);
  u += 0x7fffu + ((u >> 16) & 1u);  // round-to-nearest-even
  return (unsigned short)(u >> 16);
}

enum { ST_QKV = 0, ST_BF16 = 1, ST_F32 = 2 };

#define PH_SYNC                                                             \
  asm volatile("s_waitcnt vmcnt(4)" ::: "memory");                          \
  __builtin_amdgcn_s_barrier();                                             \
  asm volatile("s_waitcnt lgkmcnt(0)" ::: "memory");                        \
  __builtin_amdgcn_sched_barrier(0);                                        \
  __builtin_amdgcn_s_setprio(1);

#define PH_END                                                              \
  __builtin_amdgcn_s_setprio(0);                                            \
  __builtin_amdgcn_s_barrier();

// C = A * B^T, A [M x K] row-major (lda), B [N x K] row-major (ldb), bf16 in.
// BM=BN=256, BK=64. Grid: x = M/256, y = N/256, z = batch.
template <int STORE>
__global__ __launch_bounds__(512, 2) void gemm8p(
    const unsigned short* __restrict__ A, const unsigned short* __restrict__ B,
    void* __restrict__ Cout, int K, int lda, int ldb, int ldc, long aS,
    long bS, long cS, unsigned short* __restrict__ qd,
    unsigned short* __restrict__ kd, unsigned short* __restrict__ vd) {
  __shared__ unsigned short As[2][16384];
  __shared__ unsigned short Bs[2][16384];

  const int tid = threadIdx.x;
  const int lane = tid & 63;
  const int l15 = lane & 15;
  const int g = lane >> 4;
  const int wid = tid >> 6;
  const int wm = wid >> 2;   // 0..1  (M interleave)
  const int wn = wid & 3;    // 0..3  (N interleave)
  const int xorv = (l15 & 7) << 4;

  const unsigned short* Ag =
      A + (long)blockIdx.z * aS + (long)(blockIdx.x * 256) * lda;
  const unsigned short* Bg =
      B + (long)blockIdx.z * bS + (long)(blockIdx.y * 256) * ldb;

  char* Ab = (char*)&As[0][0];
  char* Bb = (char*)&Bs[0][0];

  f32x4 acc[8][4];
#pragma unroll
  for (int i = 0; i < 8; ++i)
#pragma unroll
    for (int j = 0; j < 4; ++j) acc[i][j] = (f32x4)(0.0f);

  // stage one half-tile (128 rows x 64 cols bf16 = 16 KB) of A or B.
  // LDS dest linear in chunk index; global source chunk XOR-pre-swizzled so
  // LDS holds byte(row,col) = row*128 + (col*2 ^ ((row&7)<<4)).
  auto stage = [&](const unsigned short* G, int ld, int half, int k0,
                   char* dst) {
#pragma unroll
    for (int j = 0; j < 2; ++j) {
      int c = (j << 9) | tid;  // 0..1023 16B chunks
      int r = c >> 3;          // 0..127
      int cc = c & 7;
      int sc = cc ^ (r & 7);
      GLD16(G + (long)((half << 7) + r) * ld + k0 + (sc << 3),
            dst + (half << 14) + (c << 4));
    }
  };

  auto ldA = [&](const char* base, int mi, int ks) {
    int row = ((mi * 2 + wm) << 4) + l15;  // interleaved M blocks
    return *(const short8*)(base + row * 128 +
                            (((g << 4) + (ks << 6)) ^ xorv));
  };
  auto ldB = [&](const char* base, int nj, int ks) {
    int row = ((nj * 4 + wn) << 4) + l15;  // interleaved N blocks
    return *(const short8*)(base + row * 128 +
                            (((g << 4) + (ks << 6)) ^ xorv));
  };

  const int NT = K >> 6;

  // prologue: tile 0, order A0,B0,B1,A1; vmcnt(4) => A0,B0 resident.
  stage(Ag, lda, 0, 0, Ab);
  stage(Bg, ldb, 0, 0, Bb);
  stage(Bg, ldb, 1, 0, Bb);
  stage(Ag, lda, 1, 0, Ab);
  asm volatile("s_waitcnt vmcnt(4)" ::: "memory");
  __builtin_amdgcn_s_barrier();

  for (int t = 0; t < NT; ++t) {
    const char* Ac = Ab + ((t & 1) << 15);
    const char* Bc = Bb + ((t & 1) << 15);
    char* An = Ab + (((t + 1) & 1) << 15);
    char* Bn = Bb + (((t + 1) & 1) << 15);
    const int k1 = (t + 1) << 6;
    const bool st = (t + 1) < NT;
    short8 af[4][2], bfL[2][2], bfH[2][2];

    // ---- phase 1: quadrant (mih=0, njh=0) ----
#pragma unroll
    for (int m = 0; m < 4; ++m) {
      af[m][0] = ldA(Ac, m, 0);
      af[m][1] = ldA(Ac, m, 1);
    }
#pragma unroll
    for (int n = 0; n < 2; ++n) {
      bfL[n][0] = ldB(Bc, n, 0);
      bfL[n][1] = ldB(Bc, n, 1);
    }
    if (st) stage(Ag, lda, 0, k1, An);
    PH_SYNC
#pragma unroll
    for (int m = 0; m < 4; ++m)
#pragma unroll
      for (int n = 0; n < 2; ++n)
#pragma unroll
        for (int ks = 0; ks < 2; ++ks)
          acc[m][n] = __builtin_amdgcn_mfma_f32_16x16x32_bf16(
              af[m][ks], bfL[n][ks], acc[m][n], 0, 0, 0);
    PH_END

    // ---- phase 2: quadrant (mih=0, njh=1) ----
#pragma unroll
    for (int n = 0; n < 2; ++n) {
      bfH[n][0] = ldB(Bc, 2 + n, 0);
      bfH[n][1] = ldB(Bc, 2 + n, 1);
    }
    if (st) stage(Bg, ldb, 0, k1, Bn);
    PH_SYNC
#pragma unroll
    for (int m = 0; m < 4; ++m)
#pragma unroll
      for (int n = 0; n < 2; ++n)
#pragma unroll
        for (int ks = 0; ks < 2; ++ks)
          acc[m][2 + n] = __builtin_amdgcn_mfma_f32_16x16x32_bf16(
              af[m][ks], bfH[n][ks], acc[m][2 + n], 0, 0, 0);
    PH_END

    // ---- phase 3: quadrant (mih=1, njh=0) ----
#pragma unroll
    for (int m = 0; m < 4; ++m) {
      af[m][0] = ldA(Ac, 4 + m, 0);
      af[m][1] = ldA(Ac, 4 + m, 1);
    }
    if (st) stage(Bg, ldb, 1, k1, Bn);
    PH_SYNC
#pragma unroll
    for (int m = 0; m < 4; ++m)
#pragma unroll
      for (int n = 0; n < 2; ++n)
#pragma unroll
        for (int ks = 0; ks < 2; ++ks)
          acc[4 + m][n] = __builtin_amdgcn_mfma_f32_16x16x32_bf16(
              af[m][ks], bfL[n][ks], acc[4 + m][n], 0, 0, 0);
    PH_END

    // ---- phase 4: quadrant (mih=1, njh=1) ----
    if (st) stage(Ag, lda, 1, k1, An);
    PH_SYNC
#pragma unroll
    for (int m = 0; m < 4; ++m)
#pragma unroll
      for (int n = 0; n < 2; ++n)
#pragma unroll
        for (int ks = 0; ks < 2; ++ks)
          acc[4 + m][2 + n] = __builtin_amdgcn_mfma_f32_16x16x32_bf16(
              af[m][ks], bfH[n][ks], acc[4 + m][2 + n], 0, 0, 0);
    PH_END
  }

  // Epilogue. C/D layout: col = l15 (within nj 16-block), row = g*4 + r.
  const int rbase = blockIdx.x * 256;
  const int cbase = blockIdx.y * 256;

  if (STORE == ST_F32) {
    float* C = (float*)Cout + (long)blockIdx.z * cS;
#pragma unroll
    for (int mi = 0; mi < 8; ++mi)
#pragma unroll
      for (int nj = 0; nj < 4; ++nj)
#pragma unroll
        for (int r = 0; r < 4; ++r) {
          int row = rbase + ((mi * 2 + wm) << 4) + (g << 2) + r;
          int col = cbase + ((nj * 4 + wn) << 4) + l15;
          C[(long)row * ldc + col] = acc[mi][nj][r];
        }
  } else if (STORE == ST_BF16) {
    unsigned short* C = (unsigned short*)Cout + (long)blockIdx.z * cS;
#pragma unroll
    for (int mi = 0; mi < 8; ++mi)
#pragma unroll
      for (int nj = 0; nj < 4; ++nj)
#pragma unroll
        for (int r = 0; r < 4; ++r) {
          int row = rbase + ((mi * 2 + wm) << 4) + (g << 2) + r;
          int col = cbase + ((nj * 4 + wn) << 4) + l15;
          C[(long)row * ldc + col] = f2bf(acc[mi][nj][r]);
        }
  } else {  // ST_QKV: by 0,1 -> Q; 2,3 -> K; 4,5 -> V^T [b][d][s]
    const int widx = blockIdx.y >> 1;
    unsigned short* dst = (widx == 0) ? qd : ((widx == 1) ? kd : vd);
#pragma unroll
    for (int mi = 0; mi < 8; ++mi)
#pragma unroll
      for (int nj = 0; nj < 4; ++nj)
#pragma unroll
        for (int r = 0; r < 4; ++r) {
          int row = rbase + ((mi * 2 + wm) << 4) + (g << 2) + r;  // b*1024+s
          int col = ((blockIdx.y & 1) << 8) + ((nj * 4 + wn) << 4) + l15;
          unsigned short v = f2bf(acc[mi][nj][r]);
          if (widx < 2)
            dst[(long)row * 512 + col] = v;
          else
            dst[(long)(row >> 10) * 524288 + (long)col * 1024 + (row & 1023)] =
                v;
        }
  }
}

// In-place row softmax over 32768 rows of 1024 bf16. One wave per row.
__global__ __launch_bounds__(256) void softmax_rows(
    unsigned short* __restrict__ S) {
  const long row = (long)blockIdx.x * 4 + (threadIdx.x >> 6);
  const int lane = threadIdx.x & 63;
  unsigned short* p = S + row * 1024 + lane * 16;
  uint4 u0 = *(const uint4*)p;
  uint4 u1 = *(const uint4*)(p + 8);
  unsigned int us[8] = {u0.x, u0.y, u0.z, u0.w, u1.x, u1.y, u1.z, u1.w};
  float v[16];
#pragma unroll
  for (int j = 0; j < 8; ++j) {
    v[2 * j] = __uint_as_float(us[j] << 16);
    v[2 * j + 1] = __uint_as_float(us[j] & 0xffff0000u);
  }
  float m = v[0];
#pragma unroll
  for (int i = 1; i < 16; ++i) m = fmaxf(m, v[i]);
#pragma unroll
  for (int off = 32; off >= 1; off >>= 1) m = fmaxf(m, __shfl_xor(m, off, 64));
  float s = 0.0f;
#pragma unroll
  for (int i = 0; i < 16; ++i) {
    v[i] = __expf(v[i] - m);
    s += v[i];
  }
#pragma unroll
  for (int off = 32; off >= 1; off >>= 1) s += __shfl_xor(s, off, 64);
  const float inv = 1.0f / s;
#pragma unroll
  for (int j = 0; j < 8; ++j) {
    unsigned int lo = f2bf(v[2 * j] * inv);
    unsigned int hi = f2bf(v[2 * j + 1] * inv);
    us[j] = lo | (hi << 16);
  }
  uint4 o0 = {us[0], us[1], us[2], us[3]};
  uint4 o1 = {us[4], us[5], us[6], us[7]};
  *(uint4*)p = o0;
  *(uint4*)(p + 8) = o1;
}

// Convert x and the three 512x512 weights to bf16 (Wq pre-scaled by 1/sqrt(512)).
__global__ __launch_bounds__(256) void convert_in(
    const float* __restrict__ x, const float* __restrict__ wq,
    const float* __restrict__ wk, const float* __restrict__ wv,
    unsigned short* __restrict__ xb, unsigned short* __restrict__ wb) {
  const long i = (long)blockIdx.x * 256 + threadIdx.x;
  const long NX4 = 16777216 / 4;
  const float* src;
  unsigned short* dst;
  long off;
  float sc = 1.0f;
  if (i < NX4) {
    src = x;
    dst = xb;
    off = i;
  } else {
    long r = i - NX4;
    int w = (int)(r >> 16);
    off = r & 65535;
    src = (w == 0) ? wq : (w == 1) ? wk : wv;
    dst = wb + (long)w * 262144;
    if (w == 0) sc = 0.044194173824159216f;  // 1/sqrt(512)
  }
  float4 f = ((const float4*)src)[off];
  ushort4 o;
  o.x = f2bf(f.x * sc);
  o.y = f2bf(f.y * sc);
  o.z = f2bf(f.z * sc);
  o.w = f2bf(f.w * sc);
  ((ushort4*)dst)[off] = o;
}

extern "C" void kernel_launch(void* const* d_in, const int* in_sizes, int n_in,
                              void* d_out, int out_size, void* d_ws,
                              size_t ws_size, hipStream_t stream) {
  const float* x = (const float*)d_in[0];
  const float* wq = (const float*)d_in[1];
  const float* wk = (const float*)d_in[2];
  const float* wv = (const float*)d_in[3];
  float* out = (float*)d_out;

  unsigned short* xb = (unsigned short*)d_ws;  // 16777216
  unsigned short* wb = xb + 16777216;          // 3*262144 (wq_s|wk|wv rows 0..1535)
  unsigned short* qb = wb + 786432;            // 16777216
  unsigned short* kb = qb + 16777216;          // 16777216
  unsigned short* vtb = kb + 16777216;         // 16777216 (V^T [b][d][s])
  unsigned short* sb = vtb + 16777216;         // 33554432 (S -> P in place)

  convert_in<<<17152, 256, 0, stream>>>(x, wq, wk, wv, xb, wb);

  // QKV: M=32768, N=1536, K=512
  gemm8p<ST_QKV><<<dim3(128, 6, 1), 512, 0, stream>>>(
      xb, wb, nullptr, 512, 512, 512, 0, 0L, 0L, 0L, qb, kb, vtb);

  // S = Q K^T per batch: M=N=1024, K=512
  gemm8p<ST_BF16><<<dim3(4, 4, 32), 512, 0, stream>>>(
      qb, kb, sb, 512, 512, 512, 1024, 524288L, 524288L, 1048576L, nullptr,
      nullptr, nullptr);

  softmax_rows<<<8192, 256, 0, stream>>>(sb);

  // out = P V: M=1024, N=512, K=1024
  gemm8p<ST_F32><<<dim3(4, 2, 32), 512, 0, stream>>>(
      sb, vtb, out, 1024, 1024, 1024, 512, 1048576L, 524288L, 524288L, nullptr,
      nullptr, nullptr);
}